// Round 1
// baseline (272.101 us; speedup 1.0000x reference)
//
#include <hip/hip_runtime.h>

// out[b][w][f][c] = x[b][w+f][c]
// B=128, L=4096, F=32, C=4 -> W = 4065 windows.
// C=4 fp32 = 16B = one float4 per (b,w,f). Pure memory-bound gather.

constexpr int FILTER_WIDTH = 32;
constexpr int SEQ_LEN      = 4096;
constexpr int NWIN         = SEQ_LEN - FILTER_WIDTH + 1;  // 4065
constexpr int BATCH        = 128;
constexpr long long TOTAL4 = (long long)BATCH * NWIN * FILTER_WIDTH;  // float4 count

__global__ void im2col_gather(const float4* __restrict__ x,
                              float4* __restrict__ out,
                              int total) {
    int idx    = blockIdx.x * blockDim.x + threadIdx.x;
    int stride = gridDim.x * blockDim.x;
    for (int o = idx; o < total; o += stride) {
        int f  = o & (FILTER_WIDTH - 1);     // o % 32
        int bw = o >> 5;                     // o / 32
        int w  = bw % NWIN;                  // magic-multiply div
        int b  = bw / NWIN;
        // x is [B][L] of float4
        out[o] = x[(long long)b * SEQ_LEN + w + f];
    }
}

extern "C" void kernel_launch(void* const* d_in, const int* in_sizes, int n_in,
                              void* d_out, int out_size, void* d_ws, size_t ws_size,
                              hipStream_t stream) {
    const float4* x = (const float4*)d_in[0];
    float4* out     = (float4*)d_out;

    const int total = (int)TOTAL4;           // 16,646,400 float4s
    const int block = 256;
    // memory-bound: cap grid, grid-stride the rest (256 CU * 8 blocks/CU)
    int grid = (total + block - 1) / block;
    if (grid > 2048) grid = 2048;

    im2col_gather<<<grid, block, 0, stream>>>(x, out, total);
}